// Round 2
// baseline (296.054 us; speedup 1.0000x reference)
//
#include <hip/hip_runtime.h>

// CapsNet dynamic routing, B=256, P=2048, C=10, OUT=16, IN=8, 3 iters.
// R8: uhat is NEVER materialized (was 168MB fp16 + 3 scattered re-reads =
// ~840MB HBM, 254us). Each routing iteration recomputes uhat rows on the fly
// (671M FMA ~ 10us VALU) inside one kernel over (32b x 16p) tiles:
//   K<0>: s1_raw[b,c,o] = sum_p uhat           (v,lg paths dead)
//   K<1>: v1=squash(0.1*s1), lg2 = uhat.v1 -> global (21MB, the only big
//         intermediate), c=softmax_c(lg2) in-lane, s2 += c*uhat
//   K<2>: v2=squash(s2), lg3 = lg2 + uhat.v2, c=softmax, s3 += c*uhat
//   k_out: out = squash(s3)
// Pair-split: lane=(b_l,h); each lane owns 5 c's; softmax couples halves via
// one shfl_xor(.,1). s partials: regs -> LDS wave-turn reduce -> fp32
// atomicAdd (5.2M adds total). All LDS tiles padded so row stride = 4 mod 32
// (8-way b128 spread = LDS minimum). bt=x>>7, pt=x&127 so the 8 b-tiles of a
// p-tile share an XCD (x mod 8 = pt mod 8) for W L2 reuse. fp32 throughout.

#define Bn 256
#define Pn 2048
#define Cn 10
#define On 16
#define In 8
#define ROW 160            // Cn*On
#define BT 32              // b per block
#define PT 16              // p per block
#define CHP 4              // p per chunk = waves per block
#define TPB 256
#define NCH (PT / CHP)     // 4 chunks
#define GRID ((Bn / BT) * (Pn / PT)) // 8*128 = 1024

template <int MODE>
__global__ __launch_bounds__(TPB, 2) void k_cap(const float* __restrict__ u,
                                                const float* __restrict__ W,
                                                const float* __restrict__ sPrev,
                                                float* __restrict__ sOut,
                                                float* __restrict__ lg) {
  __shared__ float uL[BT * 132];   // [32b][16p*8i + 4 pad]  16896 B
  __shared__ float vL[BT * 164];   // [32b][160 + 4 pad]     20992 B
  __shared__ float wS[CHP * 1280]; // 4p x (10c*16o*8i)      20480 B; reused as sAcc[32*160]
  const int x = blockIdx.x;
  const int bt = x >> 7;     // 8 b-tiles
  const int pt = x & 127;    // 128 p-tiles; x mod 8 == pt mod 8 -> same XCD per p-tile
  const int tid = threadIdx.x;
  const int lane = tid & 63;
  const int wid = tid >> 6;
  const int b_l = lane >> 1;
  const int h = lane & 1;
  const int b0 = bt * BT;
  const int p0 = pt * PT;

  // ---- stage u tile: 32b x 16p x 8i = 1024 float4 (512B dense runs per b) ----
  {
    const float4* uf = reinterpret_cast<const float4*>(u);
#pragma unroll
    for (int r = 0; r < 4; ++r) {
      const int f = tid + 256 * r;
      const int bl = f >> 5, c4 = f & 31;            // 32 f4 per b
      const int b = b0 + bl, p = p0 + (c4 >> 1);
      float4 v = uf[((size_t)b * Pn + p) * 2 + (c4 & 1)];
      *reinterpret_cast<float4*>(&uL[bl * 132 + c4 * 4]) = v;
    }
  }
  // ---- stage sPrev + in-place squash -> vL ----
  if (MODE >= 1) {
    const float4* sf = reinterpret_cast<const float4*>(sPrev);
#pragma unroll
    for (int r = 0; r < 5; ++r) {
      const int f = tid + 256 * r;                   // 1280 f4
      const int bl = f / 40, rem = f - 40 * bl;      // 40 f4 per b
      float4 v = sf[(b0 + bl) * 40 + rem];
      *reinterpret_cast<float4*>(&vL[bl * 164 + rem * 4]) = v;
    }
    __syncthreads();
    const float scale = (MODE == 1) ? 0.1f : 1.0f;
#pragma unroll
    for (int rr = 0; rr < 2; ++rr) {
      const int g = tid + 256 * rr;                  // 320 (b,c) cells
      if (g < BT * Cn) {
        const int bl = g / 10, c = g - 10 * bl;
        float* vp = &vL[bl * 164 + c * 16];
        float sq = 0.f;
#pragma unroll
        for (int o = 0; o < On; ++o) { const float xx = vp[o]; sq += xx * xx; }
        sq *= scale * scale;
        const float fac = scale * (sq / (1.f + sq)) / sqrtf(sq + 1e-9f);
#pragma unroll
        for (int o = 0; o < On; ++o) vp[o] *= fac;
      }
    }
  }

  float acc[5][16];
#pragma unroll
  for (int kc = 0; kc < 5; ++kc)
#pragma unroll
    for (int o = 0; o < On; ++o) acc[kc][o] = 0.f;

  for (int ch = 0; ch < NCH; ++ch) {
    __syncthreads(); // guards wS reuse (and uL/vL on first pass)
    // stage W chunk: 4p x 1280 floats = 1280 f4, 5KB dense per p
    {
      const float4* wf = reinterpret_cast<const float4*>(W);
#pragma unroll
      for (int r = 0; r < 5; ++r) {
        const int f = tid + 256 * r;
        const int pl = f / 320, rem = f - 320 * pl;
        float4 v = wf[(size_t)(p0 + ch * CHP + pl) * 320 + rem];
        *reinterpret_cast<float4*>(&wS[f * 4]) = v;
      }
    }
    __syncthreads();
    // each wave computes its one p of the chunk
    const int pidx = ch * CHP + wid;
    const int p = p0 + pidx;
    const float* wp = &wS[wid * 1280];
    float uu[8];
    {
      const float4 a = *reinterpret_cast<const float4*>(&uL[b_l * 132 + pidx * 8]);
      const float4 bv = *reinterpret_cast<const float4*>(&uL[b_l * 132 + pidx * 8 + 4]);
      uu[0] = a.x; uu[1] = a.y; uu[2] = a.z; uu[3] = a.w;
      uu[4] = bv.x; uu[5] = bv.y; uu[6] = bv.z; uu[7] = bv.w;
    }
    if (MODE == 0) {
#pragma unroll
      for (int kc = 0; kc < 5; ++kc) {
        const int c = h * 5 + kc;
        const float* wc = wp + c * 128;
#pragma unroll
        for (int o = 0; o < On; ++o) {
          const float* w8 = wc + o * 8;
          float d = w8[0] * uu[0];
#pragma unroll
          for (int i = 1; i < 8; ++i) d = __builtin_fmaf(w8[i], uu[i], d);
          acc[kc][o] += d;
        }
      }
    } else {
      float uh[5][16], lgv[5];
#pragma unroll
      for (int kc = 0; kc < 5; ++kc) {
        const int c = h * 5 + kc;
        const float* wc = wp + c * 128;
        const float* vp = &vL[b_l * 164 + c * 16];
        float lsum = 0.f;
#pragma unroll
        for (int o = 0; o < On; ++o) {
          const float* w8 = wc + o * 8;
          float d = w8[0] * uu[0];
#pragma unroll
          for (int i = 1; i < 8; ++i) d = __builtin_fmaf(w8[i], uu[i], d);
          uh[kc][o] = d;
          lsum = __builtin_fmaf(d, vp[o], lsum);
        }
        lgv[kc] = lsum;
      }
      const int bG = b0 + b_l;
      float* lrow = lg + ((size_t)p * Bn + bG) * Cn + h * 5;
      if (MODE == 2) {
#pragma unroll
        for (int kc = 0; kc < 5; ++kc) lgv[kc] += lrow[kc];
      } else {
#pragma unroll
        for (int kc = 0; kc < 5; ++kc) lrow[kc] = lgv[kc];
      }
      // softmax over 10 c's: 5 in-lane + cross-half via one shuffle
      float m = lgv[0];
#pragma unroll
      for (int kc = 1; kc < 5; ++kc) m = fmaxf(m, lgv[kc]);
      m = fmaxf(m, __shfl_xor(m, 1, 64));
      float e[5], ss = 0.f;
#pragma unroll
      for (int kc = 0; kc < 5; ++kc) { e[kc] = __expf(lgv[kc] - m); ss += e[kc]; }
      ss += __shfl_xor(ss, 1, 64);
      const float inv = 1.f / ss;
#pragma unroll
      for (int kc = 0; kc < 5; ++kc) {
        const float cv = e[kc] * inv;
#pragma unroll
        for (int o = 0; o < On; ++o)
          acc[kc][o] = __builtin_fmaf(cv, uh[kc][o], acc[kc][o]);
      }
    }
  }

  // ---- cross-wave reduce in LDS (wS reused as sAcc[32][160], exact fit) ----
  float* sAcc = wS;
#pragma unroll
  for (int r = 0; r < 4; ++r) {
    __syncthreads();
    if (wid == r) {
      float* dst = &sAcc[b_l * 160 + h * 80];
      if (r == 0) {
#pragma unroll
        for (int kc = 0; kc < 5; ++kc)
#pragma unroll
          for (int o = 0; o < On; ++o) dst[kc * 16 + o] = acc[kc][o];
      } else {
#pragma unroll
        for (int kc = 0; kc < 5; ++kc)
#pragma unroll
          for (int o = 0; o < On; ++o) dst[kc * 16 + o] += acc[kc][o];
      }
    }
  }
  __syncthreads();
  for (int e2 = tid; e2 < BT * ROW; e2 += TPB) {
    const int bl = e2 / 160, rem = e2 - 160 * bl;
    atomicAdd(&sOut[(size_t)(b0 + bl) * ROW + rem], sAcc[e2]);
  }
}

__global__ __launch_bounds__(256) void k_out(const float* __restrict__ s,
                                             float* __restrict__ out) {
  const int g = blockIdx.x * 256 + threadIdx.x; // [0, 2560) = (b,c)
  const int b = g / 10, c = g - 10 * b;
  const float* sp = s + (size_t)b * ROW + c * 16;
  float sq = 0.f;
#pragma unroll
  for (int o = 0; o < On; ++o) { const float xx = sp[o]; sq += xx * xx; }
  const float fac = (sq / (1.f + sq)) / sqrtf(sq + 1e-9f);
  float* op = out + (size_t)b * ROW + c * 16;
#pragma unroll
  for (int o = 0; o < On; ++o) op[o] = fac * sp[o];
}

extern "C" void kernel_launch(void* const* d_in, const int* in_sizes, int n_in,
                              void* d_out, int out_size, void* d_ws, size_t ws_size,
                              hipStream_t stream) {
  (void)in_sizes; (void)n_in; (void)out_size;
  const float* u = (const float*)d_in[0];
  const float* W = (const float*)d_in[1];
  float* out = (float*)d_out;
  float* s1 = (float*)d_ws;                 // [256][160] fp32
  float* s2 = s1 + (size_t)Bn * ROW;
  float* s3 = s2 + (size_t)Bn * ROW;
  float* lg = s3 + (size_t)Bn * ROW;        // [2048][256][10] fp32, 21MB
  const size_t need = ((size_t)3 * Bn * ROW + (size_t)Pn * Bn * Cn) * sizeof(float);
  if (ws_size < need) return;
  hipMemsetAsync(d_ws, 0, (size_t)3 * Bn * ROW * sizeof(float), stream);
  k_cap<0><<<GRID, TPB, 0, stream>>>(u, W, s1, s1, lg);
  k_cap<1><<<GRID, TPB, 0, stream>>>(u, W, s1, s2, lg);
  k_cap<2><<<GRID, TPB, 0, stream>>>(u, W, s2, s3, lg);
  k_out<<<10, 256, 0, stream>>>(s3, out);
}